// Round 3
// baseline (9768.646 us; speedup 1.0000x reference)
//
#include <hip/hip_runtime.h>
#include <hip/hip_bf16.h>
#include <math.h>

#define B 512
#define N 50
#define D 768
#define G4 3072
#define BN (B*N)        // 25600
#define FLAT (N*D)      // 38400 per-batch flat length for EGCE
#define KT 16

typedef __hip_bfloat16 bf16;

__device__ __forceinline__ float b2f(bf16 x){ return __bfloat162float(x); }
__device__ __forceinline__ float sigf(float x){ return 1.0f/(1.0f+expf(-x)); }

// ---------------- Kernel A: EGCE channel means + attention gates (3 modalities) ----
__global__ __launch_bounds__(256) void egce_att(
    const float* __restrict__ text, const int* __restrict__ vid, const int* __restrict__ aid,
    const float* __restrict__ vemb, const float* __restrict__ aemb, const float* __restrict__ egw,
    float* __restrict__ att_t, float* __restrict__ att_v, float* __restrict__ att_a){
  int b = blockIdx.x; int tid = threadIdx.x;
  __shared__ float gt[D+2], gv[D+2], ga[D+2];
  float w0 = egw[0], w1 = egw[1], w2 = egw[2];
  if(tid==0){ gt[0]=gv[0]=ga[0]=0.f; gt[D+1]=gv[D+1]=ga[D+1]=0.f; }
  const float* tb = text + (size_t)b*FLAT;
  const int* vb_ = vid + b*N; const int* ab_ = aid + b*N;
  for(int ch = tid; ch < D; ch += 256){
    float st=0.f, sv=0.f, sa=0.f;
    int j0 = ch*50;
    for(int p=0;p<50;p++){
      int j = j0+p; int n = j/D; int d = j - n*D;
      st += tb[j];
      float vv = vemb[vb_[n]*D + d]; sv += vv>0.f?vv:0.f;
      sa += aemb[ab_[n]*D + d];
    }
    gt[ch+1]=st*(1.f/50.f); gv[ch+1]=sv*(1.f/50.f); ga[ch+1]=sa*(1.f/50.f);
  }
  __syncthreads();
  for(int ch = tid; ch < D; ch += 256){
    att_t[b*D+ch] = sigf(w0*gt[ch]+w1*gt[ch+1]+w2*gt[ch+2]);
    att_v[b*D+ch] = sigf(w0*gv[ch]+w1*gv[ch+1]+w2*gv[ch+2]);
    att_a[b*D+ch] = sigf(w0*ga[ch]+w1*ga[ch+1]+w2*ga[ch+2]);
  }
}

// ---------------- Kernel B: per-batch sums of gated modalities ----------------------
__global__ __launch_bounds__(256) void gate_sums(
    const float* __restrict__ text, const int* __restrict__ vid, const int* __restrict__ aid,
    const float* __restrict__ vemb, const float* __restrict__ aemb,
    const float* __restrict__ att_t, const float* __restrict__ att_v, const float* __restrict__ att_a,
    float* __restrict__ tsum, float* __restrict__ vsum, float* __restrict__ asum){
  int b = blockIdx.x; int tid = threadIdx.x;
  float ta[3]={0,0,0}, va[3]={0,0,0}, aa[3]={0,0,0};
  const float* At = att_t + b*D; const float* Av = att_v + b*D; const float* Aa = att_a + b*D;
  for(int n=0;n<N;n++){
    int id_v = vid[b*N+n]; int id_a = aid[b*N+n];
    for(int q=0;q<3;q++){
      int d = q*256 + tid;
      int ch = (n*D + d)/50;
      size_t gi = ((size_t)b*N+n)*D + d;
      ta[q] += text[gi] * At[ch];
      float vv = vemb[id_v*D+d]; vv = vv>0.f?vv:0.f;
      va[q] += vv * Av[ch];
      aa[q] += aemb[id_a*D+d] * Aa[ch];
    }
  }
  for(int q=0;q<3;q++){
    int d=q*256+tid;
    tsum[b*D+d]=ta[q]; vsum[b*D+d]=va[q]; asum[b*D+d]=aa[q];
  }
}

// ---------------- Kernel C: cosine sims + masks -----------------------------------
__global__ __launch_bounds__(256) void cos_masks(
    const float* __restrict__ tsum, const float* __restrict__ vsum,
    const float* __restrict__ asum, int* __restrict__ m1, int* __restrict__ m2){
  int b=blockIdx.x, tid=threadIdx.x;
  float tt=0,vv=0,aa=0,tv=0,ta=0,va=0;
  for(int d=tid; d<D; d+=256){
    float t=tsum[b*D+d]*(1.f/50.f), v=vsum[b*D+d]*(1.f/50.f), a=asum[b*D+d]*(1.f/50.f);
    tt+=t*t; vv+=v*v; aa+=a*a; tv+=t*v; ta+=t*a; va+=v*a;
  }
  __shared__ float red[6][256];
  red[0][tid]=tt; red[1][tid]=vv; red[2][tid]=aa; red[3][tid]=tv; red[4][tid]=ta; red[5][tid]=va;
  __syncthreads();
  for(int s=128;s>0;s>>=1){
    if(tid<s){ for(int r=0;r<6;r++) red[r][tid]+=red[r][tid+s]; }
    __syncthreads();
  }
  if(tid==0){
    float nt=fmaxf(sqrtf(red[0][0]),1e-8f), nv=fmaxf(sqrtf(red[1][0]),1e-8f), na=fmaxf(sqrtf(red[2][0]),1e-8f);
    float rtv=red[3][0]/(nt*nv), rta=red[4][0]/(nt*na), rva=red[5][0]/(nv*na);
    float delta=(rtv+rta+rva)*(1.f/3.f);
    float joint=(rtv+rta+rva)*(1.f/3.f);
    m1[b] = (rtv>delta && rta>delta && rva>delta) ? 1:0;
    m2[b] = (joint>delta) ? 1:0;
  }
}

#define FMA16 \
  acc[0][0]+=a4.x*b4.x; acc[0][1]+=a4.x*b4.y; acc[0][2]+=a4.x*b4.z; acc[0][3]+=a4.x*b4.w; \
  acc[1][0]+=a4.y*b4.x; acc[1][1]+=a4.y*b4.y; acc[1][2]+=a4.y*b4.z; acc[1][3]+=a4.y*b4.w; \
  acc[2][0]+=a4.z*b4.x; acc[2][1]+=a4.z*b4.y; acc[2][2]+=a4.z*b4.z; acc[2][3]+=a4.z*b4.w; \
  acc[3][0]+=a4.w*b4.x; acc[3][1]+=a4.w*b4.y; acc[3][2]+=a4.w*b4.z; acc[3][3]+=a4.w*b4.w;

// ---------------- Kernel D: f_cross per-batch = (vsum@vW0.T + asum@(vW1+vW2).T + bias)/3
__global__ __launch_bounds__(256) void fcross_gemm(
    const float* __restrict__ vsum, const float* __restrict__ asum,
    const float* __restrict__ vW, const float* __restrict__ vbias, float* __restrict__ fcross){
  __shared__ float As[KT][68], Bs[KT][68];
  int bx=blockIdx.x, by=blockIdx.y, tid=threadIdx.x;
  int tx=tid&15, ty=tid>>4;
  float acc[4][4]={};
  int kl=tid&15, g4=tid>>4;
  const float* W0 = vW;
  const float* W1 = vW + D*D;
  const float* W2 = vW + 2*D*D;
  for(int ph=0; ph<2; ph++){
    const float* A = ph? asum : vsum;
    for(int k0=0;k0<D;k0+=KT){
      for(int i=0;i<4;i++){
        int ml=g4*4+i;
        As[kl][ml] = A[(by*64+ml)*D + k0+kl];
        int d = bx*64+ml;
        float w = ph ? (W1[(size_t)d*D+k0+kl] + W2[(size_t)d*D+k0+kl])
                     : W0[(size_t)d*D+k0+kl];
        Bs[kl][ml]=w;
      }
      __syncthreads();
      #pragma unroll
      for(int k=0;k<KT;k++){
        float4 a4=*(const float4*)&As[k][ty*4];
        float4 b4=*(const float4*)&Bs[k][tx*4];
        FMA16
      }
      __syncthreads();
    }
  }
  for(int i=0;i<4;i++)for(int j=0;j<4;j++){
    int bb = by*64+ty*4+i; int d = bx*64+tx*4+j;
    float bias = 50.f*(vbias[d] + vbias[D+d] + vbias[2*D+d]);
    fcross[bb*D+d] = (acc[i][j] + bias) * (1.f/3.f);
  }
}

// ---------------- Kernel E0: pre-LN fusion = f_cross (bcast over n) + gated text ----
__global__ __launch_bounds__(256) void fuse_pre(
    const float* __restrict__ text, const float* __restrict__ att_t,
    const float* __restrict__ fcross, bf16* __restrict__ shift){
  size_t idx = (size_t)blockIdx.x*256 + threadIdx.x;
  int d = (int)(idx % D); size_t bn = idx / D; int b = (int)(bn / N); int n = (int)(bn - (size_t)b*N);
  int ch = (n*D + d)/50;
  float tg = text[idx] * att_t[b*D+ch];
  shift[idx] = __float2bfloat16(fcross[b*D+d] + tg);
}

// ---------------- mask-gated concat/hybrid overwrite (provably never fires) --------
__global__ __launch_bounds__(256) void cond_fusion(
    const int* __restrict__ m1, const int* __restrict__ m2, int which,
    const int* __restrict__ vid, const int* __restrict__ aid,
    const float* __restrict__ vemb, const float* __restrict__ aemb,
    const float* __restrict__ att_t, const float* __restrict__ att_v, const float* __restrict__ att_a,
    const float* __restrict__ W, const float* __restrict__ bias,
    const float* __restrict__ text, bf16* __restrict__ shift){
  int b = blockIdx.x;
  bool fire = (which==0) ? (m1[b]!=0) : (m1[b]==0 && m2[b]!=0);
  if(!fire) return;
  __shared__ float cat[3*D];
  int tid=threadIdx.x;
  for(int n=0;n<N;n++){
    int idv = vid[b*N+n], ida = aid[b*N+n];
    for(int q=tid;q<D;q+=256){
      int ch=(n*D+q)/50;
      cat[q] = text[((size_t)b*N+n)*D+q] * att_t[b*D+ch];
      float vv=vemb[idv*D+q]; vv=vv>0.f?vv:0.f;
      cat[D+q]=vv*att_v[b*D+ch];
      cat[2*D+q]=aemb[ida*D+q]*att_a[b*D+ch];
    }
    __syncthreads();
    for(int d=tid; d<D; d+=256){
      float s=0.f;
      for(int k=0;k<3*D;k++) s += cat[k]*W[(size_t)d*3*D+k];
      size_t gi = ((size_t)b*N+n)*D+d;
      int ch=(n*D+d)/50;
      float tg = text[gi] * att_t[b*D+ch];
      shift[gi] = __float2bfloat16(s + bias[d] + tg);
    }
    __syncthreads();
  }
}

// ---------------- Kernel E1: LayerNorm rows in place (bf16) -------------------------
__global__ __launch_bounds__(256) void ln_rows(
    bf16* __restrict__ shift, const float* __restrict__ lng, const float* __restrict__ lnb){
  int row = blockIdx.x; int tid=threadIdx.x;
  bf16* x = shift + (size_t)row*D;
  float v[3];
  for(int q=0;q<3;q++) v[q]=b2f(x[q*256+tid]);
  __shared__ float red[256];
  red[tid]=v[0]+v[1]+v[2]; __syncthreads();
  for(int st=128;st>0;st>>=1){ if(tid<st) red[tid]+=red[tid+st]; __syncthreads(); }
  float m = red[0]*(1.f/768.f);
  __syncthreads();
  float s2=0.f;
  for(int q=0;q<3;q++){ float dl=v[q]-m; s2+=dl*dl; }
  red[tid]=s2; __syncthreads();
  for(int st=128;st>0;st>>=1){ if(tid<st) red[tid]+=red[tid+st]; __syncthreads(); }
  float var = red[0]*(1.f/768.f);
  float rs = 1.f/sqrtf(var+1e-5f);
  for(int q=0;q<3;q++){
    int d=q*256+tid;
    x[d]=__float2bfloat16((v[q]-m)*rs*lng[d]+lnb[d]);
  }
}

// ---------------- zero init h0 and c ------------------------------------------------
__global__ __launch_bounds__(256) void zero_init(float* __restrict__ cbuf, float* __restrict__ h0){
  size_t i=(size_t)blockIdx.x*256+threadIdx.x;
  if(i<(size_t)B*D){ cbuf[i]=0.f; h0[i]=0.f; }
}

// ---- LSTM step (fused x-projection): gates = shift[:,t,:]@Wih.T + h@Whh.T + b -----
__global__ __launch_bounds__(256) void lstm_step_fused(
    const float* __restrict__ hprev, float* __restrict__ hnext, float* __restrict__ cbuf,
    const bf16* __restrict__ shift, const float* __restrict__ Wih, const float* __restrict__ Whh,
    const float* __restrict__ bih, const float* __restrict__ bhh,
    const float* __restrict__ text, const float* __restrict__ att_t,
    float* __restrict__ out, int t){
  __shared__ float As[KT][68], Bs[KT][68];
  __shared__ float gbuf[64][68];
  int bx=blockIdx.x;   // 48 hidden blocks of 16 (x4 gates packed in 64 cols)
  int by=blockIdx.y;   // 8 batch blocks of 64
  int tid=threadIdx.x, tx=tid&15, ty=tid>>4;
  float acc[4][4]={};
  int kl=tid&15, g4=tid>>4;
  for(int ph=0; ph<2; ph++){
    const float* Wp = ph ? Whh : Wih;
    for(int k0=0;k0<D;k0+=KT){
      for(int i=0;i<4;i++){
        int ml=g4*4+i;
        if(ph==0){
          int b=by*64+ml;
          As[kl][ml]=b2f(shift[((size_t)b*N+t)*D + k0+kl]);
        } else {
          As[kl][ml]=hprev[(by*64+ml)*D + k0+kl];
        }
        int gate=ml>>4, hd=ml&15;
        int row=gate*D + bx*16 + hd;
        Bs[kl][ml]=Wp[(size_t)row*D + k0+kl];
      }
      __syncthreads();
      #pragma unroll
      for(int k=0;k<KT;k++){
        float4 a4=*(const float4*)&As[k][ty*4];
        float4 b4=*(const float4*)&Bs[k][tx*4];
        FMA16
      }
      __syncthreads();
    }
  }
  for(int i=0;i<4;i++)for(int j=0;j<4;j++) gbuf[ty*4+i][tx*4+j]=acc[i][j];
  __syncthreads();
  for(int p=tid;p<64*16;p+=256){
    int bl=p>>4, hd=p&15;
    int b=by*64+bl; int dg=bx*16+hd;
    float gi=gbuf[bl][hd]     + bih[dg]      + bhh[dg];
    float gf=gbuf[bl][16+hd]  + bih[D+dg]    + bhh[D+dg];
    float gg=gbuf[bl][32+hd]  + bih[2*D+dg]  + bhh[2*D+dg];
    float go=gbuf[bl][48+hd]  + bih[3*D+dg]  + bhh[3*D+dg];
    float c_old=cbuf[(size_t)b*D+dg];
    float cn=sigf(gf)*c_old + sigf(gi)*tanhf(gg);
    float hn=sigf(go)*tanhf(cn);
    cbuf[(size_t)b*D+dg]=cn;
    hnext[(size_t)b*D+dg]=hn;
    size_t oidx=((size_t)b*N+t)*D+dg;
    int ch=(t*D+dg)/50;
    float tg = text[oidx] * att_t[b*D+ch];
    out[oidx]=hn + tg;
  }
}

extern "C" void kernel_launch(void* const* d_in, const int* in_sizes, int n_in,
                              void* d_out, int out_size, void* d_ws, size_t ws_size,
                              hipStream_t stream){
  const float* text=(const float*)d_in[0];
  const int*  vid =(const int*) d_in[1];
  const int*  aid =(const int*) d_in[2];
  const float* vemb=(const float*)d_in[3];
  const float* aemb=(const float*)d_in[4];
  const float* egw =(const float*)d_in[5];
  const float* Wih =(const float*)d_in[6];
  const float* Whh =(const float*)d_in[7];
  const float* bih =(const float*)d_in[8];
  const float* bhh =(const float*)d_in[9];
  const float* lng =(const float*)d_in[10];
  const float* lnb =(const float*)d_in[11];
  const float* cW  =(const float*)d_in[12];
  const float* cb  =(const float*)d_in[13];
  const float* hW  =(const float*)d_in[14];
  const float* hb  =(const float*)d_in[15];
  const float* vW  =(const float*)d_in[20];
  const float* vb  =(const float*)d_in[21];
  float* out = (float*)d_out;

  // ---- workspace layout (total ~55.3 MB, proven safe in R2) ----
  float* W = (float*)d_ws;
  const size_t S = (size_t)B*D;         // 393216 floats (1.5 MB)
  float* att_t = W;
  float* att_v = att_t + S;
  float* att_a = att_v + S;
  float* tsum  = att_a + S;
  float* vsum  = tsum + S;
  float* asum  = vsum + S;
  float* fcross= asum + S;
  float* cbuf  = fcross + S;
  float* h0    = cbuf + S;
  float* h1    = h0 + S;                // 10*S floats = 15.7 MB
  int*   m1    = (int*)(h1 + S);
  int*   m2    = m1 + B;
  bf16*  shift = (bf16*)(m2 + B);       // BN*D bf16 = 39.3 MB

  egce_att<<<B,256,0,stream>>>(text,vid,aid,vemb,aemb,egw,att_t,att_v,att_a);
  gate_sums<<<B,256,0,stream>>>(text,vid,aid,vemb,aemb,att_t,att_v,att_a,
                                tsum,vsum,asum);
  cos_masks<<<B,256,0,stream>>>(tsum,vsum,asum,m1,m2);
  fcross_gemm<<<dim3(12,8),256,0,stream>>>(vsum,asum,vW,vb,fcross);
  fuse_pre<<<(unsigned)(((size_t)BN*D)/256),256,0,stream>>>(text,att_t,fcross,shift);
  cond_fusion<<<B,256,0,stream>>>(m1,m2,0,vid,aid,vemb,aemb,att_t,att_v,att_a,cW,cb,text,shift);
  cond_fusion<<<B,256,0,stream>>>(m1,m2,1,vid,aid,vemb,aemb,att_t,att_v,att_a,hW,hb,text,shift);
  ln_rows<<<BN,256,0,stream>>>(shift,lng,lnb);
  zero_init<<<(unsigned)((S+255)/256),256,0,stream>>>(cbuf,h0);
  for(int t=0;t<N;t++){
    float* hp = (t&1)? h1 : h0;
    float* hn = (t&1)? h0 : h1;
    lstm_step_fused<<<dim3(48,8),256,0,stream>>>(hp,hn,cbuf,shift,Wih,Whh,bih,bhh,
                                                 text,att_t,out,t);
  }
}

// Round 4
// 1778.865 us; speedup vs baseline: 5.4915x; 5.4915x over previous
//
#include <hip/hip_runtime.h>
#include <hip/hip_bf16.h>
#include <math.h>

#define B 512
#define N 50
#define D 768
#define G4 3072
#define BN (B*N)        // 25600
#define FLAT (N*D)      // 38400
#define KT 16
#define TCH 10          // timesteps per xg chunk
#define NCHUNK (N/TCH)  // 5

typedef __hip_bfloat16 bf16;
typedef short short8 __attribute__((ext_vector_type(8)));
typedef float floatx4 __attribute__((ext_vector_type(4)));

__device__ __forceinline__ float b2f(bf16 x){ return __bfloat162float(x); }
__device__ __forceinline__ float sigf(float x){ return 1.0f/(1.0f+expf(-x)); }
__device__ __forceinline__ float u2f(unsigned short u){ return __uint_as_float(((unsigned int)u)<<16); }
__device__ __forceinline__ unsigned short f2u(float f){ bf16 h=__float2bfloat16(f); return *(unsigned short*)&h; }

// ---------------- Kernel A: EGCE channel means + attention gates --------------------
__global__ __launch_bounds__(256) void egce_att(
    const float* __restrict__ text, const int* __restrict__ vid, const int* __restrict__ aid,
    const float* __restrict__ vemb, const float* __restrict__ aemb, const float* __restrict__ egw,
    float* __restrict__ att_t, float* __restrict__ att_v, float* __restrict__ att_a){
  int b = blockIdx.x; int tid = threadIdx.x;
  __shared__ float gt[D+2], gv[D+2], ga[D+2];
  float w0 = egw[0], w1 = egw[1], w2 = egw[2];
  if(tid==0){ gt[0]=gv[0]=ga[0]=0.f; gt[D+1]=gv[D+1]=ga[D+1]=0.f; }
  const float* tb = text + (size_t)b*FLAT;
  const int* vb_ = vid + b*N; const int* ab_ = aid + b*N;
  for(int ch = tid; ch < D; ch += 256){
    float st=0.f, sv=0.f, sa=0.f;
    int j0 = ch*50;
    for(int p=0;p<50;p++){
      int j = j0+p; int n = j/D; int d = j - n*D;
      st += tb[j];
      float vv = vemb[vb_[n]*D + d]; sv += vv>0.f?vv:0.f;
      sa += aemb[ab_[n]*D + d];
    }
    gt[ch+1]=st*(1.f/50.f); gv[ch+1]=sv*(1.f/50.f); ga[ch+1]=sa*(1.f/50.f);
  }
  __syncthreads();
  for(int ch = tid; ch < D; ch += 256){
    att_t[b*D+ch] = sigf(w0*gt[ch]+w1*gt[ch+1]+w2*gt[ch+2]);
    att_v[b*D+ch] = sigf(w0*gv[ch]+w1*gv[ch+1]+w2*gv[ch+2]);
    att_a[b*D+ch] = sigf(w0*ga[ch]+w1*ga[ch+1]+w2*ga[ch+2]);
  }
}

// ---------------- Kernel B: per-batch sums of gated modalities ----------------------
__global__ __launch_bounds__(256) void gate_sums(
    const float* __restrict__ text, const int* __restrict__ vid, const int* __restrict__ aid,
    const float* __restrict__ vemb, const float* __restrict__ aemb,
    const float* __restrict__ att_t, const float* __restrict__ att_v, const float* __restrict__ att_a,
    float* __restrict__ tsum, float* __restrict__ vsum, float* __restrict__ asum){
  int b = blockIdx.x; int tid = threadIdx.x;
  float ta[3]={0,0,0}, va[3]={0,0,0}, aa[3]={0,0,0};
  const float* At = att_t + b*D; const float* Av = att_v + b*D; const float* Aa = att_a + b*D;
  for(int n=0;n<N;n++){
    int id_v = vid[b*N+n]; int id_a = aid[b*N+n];
    for(int q=0;q<3;q++){
      int d = q*256 + tid;
      int ch = (n*D + d)/50;
      size_t gi = ((size_t)b*N+n)*D + d;
      ta[q] += text[gi] * At[ch];
      float vv = vemb[id_v*D+d]; vv = vv>0.f?vv:0.f;
      va[q] += vv * Av[ch];
      aa[q] += aemb[id_a*D+d] * Aa[ch];
    }
  }
  for(int q=0;q<3;q++){
    int d=q*256+tid;
    tsum[b*D+d]=ta[q]; vsum[b*D+d]=va[q]; asum[b*D+d]=aa[q];
  }
}

// ---------------- Kernel C: cosine sims + masks -------------------------------------
__global__ __launch_bounds__(256) void cos_masks(
    const float* __restrict__ tsum, const float* __restrict__ vsum,
    const float* __restrict__ asum, int* __restrict__ m1, int* __restrict__ m2){
  int b=blockIdx.x, tid=threadIdx.x;
  float tt=0,vv=0,aa=0,tv=0,ta=0,va=0;
  for(int d=tid; d<D; d+=256){
    float t=tsum[b*D+d]*(1.f/50.f), v=vsum[b*D+d]*(1.f/50.f), a=asum[b*D+d]*(1.f/50.f);
    tt+=t*t; vv+=v*v; aa+=a*a; tv+=t*v; ta+=t*a; va+=v*a;
  }
  __shared__ float red[6][256];
  red[0][tid]=tt; red[1][tid]=vv; red[2][tid]=aa; red[3][tid]=tv; red[4][tid]=ta; red[5][tid]=va;
  __syncthreads();
  for(int s=128;s>0;s>>=1){
    if(tid<s){ for(int r=0;r<6;r++) red[r][tid]+=red[r][tid+s]; }
    __syncthreads();
  }
  if(tid==0){
    float nt=fmaxf(sqrtf(red[0][0]),1e-8f), nv=fmaxf(sqrtf(red[1][0]),1e-8f), na=fmaxf(sqrtf(red[2][0]),1e-8f);
    float rtv=red[3][0]/(nt*nv), rta=red[4][0]/(nt*na), rva=red[5][0]/(nv*na);
    float delta=(rtv+rta+rva)*(1.f/3.f);
    float joint=(rtv+rta+rva)*(1.f/3.f);
    m1[b] = (rtv>delta && rta>delta && rva>delta) ? 1:0;
    m2[b] = (joint>delta) ? 1:0;
  }
}

#define FMA16 \
  acc[0][0]+=a4.x*b4.x; acc[0][1]+=a4.x*b4.y; acc[0][2]+=a4.x*b4.z; acc[0][3]+=a4.x*b4.w; \
  acc[1][0]+=a4.y*b4.x; acc[1][1]+=a4.y*b4.y; acc[1][2]+=a4.y*b4.z; acc[1][3]+=a4.y*b4.w; \
  acc[2][0]+=a4.z*b4.x; acc[2][1]+=a4.z*b4.y; acc[2][2]+=a4.z*b4.z; acc[2][3]+=a4.z*b4.w; \
  acc[3][0]+=a4.w*b4.x; acc[3][1]+=a4.w*b4.y; acc[3][2]+=a4.w*b4.z; acc[3][3]+=a4.w*b4.w;

// ---------------- Kernel D: f_cross per-batch ---------------------------------------
__global__ __launch_bounds__(256) void fcross_gemm(
    const float* __restrict__ vsum, const float* __restrict__ asum,
    const float* __restrict__ vW, const float* __restrict__ vbias, float* __restrict__ fcross){
  __shared__ float As[KT][68], Bs[KT][68];
  int bx=blockIdx.x, by=blockIdx.y, tid=threadIdx.x;
  int tx=tid&15, ty=tid>>4;
  float acc[4][4]={};
  int kl=tid&15, g4=tid>>4;
  const float* W0 = vW;
  const float* W1 = vW + D*D;
  const float* W2 = vW + 2*D*D;
  for(int ph=0; ph<2; ph++){
    const float* A = ph? asum : vsum;
    for(int k0=0;k0<D;k0+=KT){
      for(int i=0;i<4;i++){
        int ml=g4*4+i;
        As[kl][ml] = A[(by*64+ml)*D + k0+kl];
        int d = bx*64+ml;
        float w = ph ? (W1[(size_t)d*D+k0+kl] + W2[(size_t)d*D+k0+kl])
                     : W0[(size_t)d*D+k0+kl];
        Bs[kl][ml]=w;
      }
      __syncthreads();
      #pragma unroll
      for(int k=0;k<KT;k++){
        float4 a4=*(const float4*)&As[k][ty*4];
        float4 b4=*(const float4*)&Bs[k][tx*4];
        FMA16
      }
      __syncthreads();
    }
  }
  for(int i=0;i<4;i++)for(int j=0;j<4;j++){
    int bb = by*64+ty*4+i; int d = bx*64+tx*4+j;
    float bias = 50.f*(vbias[d] + vbias[D+d] + vbias[2*D+d]);
    fcross[bb*D+d] = (acc[i][j] + bias) * (1.f/3.f);
  }
}

// ---------------- Kernel E0: pre-LN fusion ------------------------------------------
__global__ __launch_bounds__(256) void fuse_pre(
    const float* __restrict__ text, const float* __restrict__ att_t,
    const float* __restrict__ fcross, bf16* __restrict__ shift){
  size_t idx = (size_t)blockIdx.x*256 + threadIdx.x;
  int d = (int)(idx % D); size_t bn = idx / D; int b = (int)(bn / N); int n = (int)(bn - (size_t)b*N);
  int ch = (n*D + d)/50;
  float tg = text[idx] * att_t[b*D+ch];
  shift[idx] = __float2bfloat16(fcross[b*D+d] + tg);
}

// ---------------- mask-gated concat/hybrid overwrite (provably never fires) ---------
__global__ __launch_bounds__(256) void cond_fusion(
    const int* __restrict__ m1, const int* __restrict__ m2, int which,
    const int* __restrict__ vid, const int* __restrict__ aid,
    const float* __restrict__ vemb, const float* __restrict__ aemb,
    const float* __restrict__ att_t, const float* __restrict__ att_v, const float* __restrict__ att_a,
    const float* __restrict__ W, const float* __restrict__ bias,
    const float* __restrict__ text, bf16* __restrict__ shift){
  int b = blockIdx.x;
  bool fire = (which==0) ? (m1[b]!=0) : (m1[b]==0 && m2[b]!=0);
  if(!fire) return;
  __shared__ float cat[3*D];
  int tid=threadIdx.x;
  for(int n=0;n<N;n++){
    int idv = vid[b*N+n], ida = aid[b*N+n];
    for(int q=tid;q<D;q+=256){
      int ch=(n*D+q)/50;
      cat[q] = text[((size_t)b*N+n)*D+q] * att_t[b*D+ch];
      float vv=vemb[idv*D+q]; vv=vv>0.f?vv:0.f;
      cat[D+q]=vv*att_v[b*D+ch];
      cat[2*D+q]=aemb[ida*D+q]*att_a[b*D+ch];
    }
    __syncthreads();
    for(int d=tid; d<D; d+=256){
      float s=0.f;
      for(int k=0;k<3*D;k++) s += cat[k]*W[(size_t)d*3*D+k];
      size_t gi = ((size_t)b*N+n)*D+d;
      int ch=(n*D+d)/50;
      float tg = text[gi] * att_t[b*D+ch];
      shift[gi] = __float2bfloat16(s + bias[d] + tg);
    }
    __syncthreads();
  }
}

// ---------------- Kernel E1: LayerNorm rows in place (bf16) -------------------------
__global__ __launch_bounds__(256) void ln_rows(
    bf16* __restrict__ shift, const float* __restrict__ lng, const float* __restrict__ lnb){
  int row = blockIdx.x; int tid=threadIdx.x;
  bf16* x = shift + (size_t)row*D;
  float v[3];
  for(int q=0;q<3;q++) v[q]=b2f(x[q*256+tid]);
  __shared__ float red[256];
  red[tid]=v[0]+v[1]+v[2]; __syncthreads();
  for(int st=128;st>0;st>>=1){ if(tid<st) red[tid]+=red[tid+st]; __syncthreads(); }
  float m = red[0]*(1.f/768.f);
  __syncthreads();
  float s2=0.f;
  for(int q=0;q<3;q++){ float dl=v[q]-m; s2+=dl*dl; }
  red[tid]=s2; __syncthreads();
  for(int st=128;st>0;st>>=1){ if(tid<st) red[tid]+=red[tid+st]; __syncthreads(); }
  float var = red[0]*(1.f/768.f);
  float rs = 1.f/sqrtf(var+1e-5f);
  for(int q=0;q<3;q++){
    int d=q*256+tid;
    x[d]=__float2bfloat16((v[q]-m)*rs*lng[d]+lnb[d]);
  }
}

// ---- weight prep: gate-interleaved permutation n' = dg*4+g, fp32 -> bf16 ----------
__global__ __launch_bounds__(256) void prep_weights(
    const float* __restrict__ Wih, const float* __restrict__ Whh,
    const float* __restrict__ bih, const float* __restrict__ bhh,
    unsigned short* __restrict__ WihP, unsigned short* __restrict__ WhhP,
    float* __restrict__ bsum){
  int np = blockIdx.x;            // 0..3071
  int dg = np>>2, g = np&3;       // hidden unit, gate (i,f,g,o)
  size_t src = (size_t)(g*D+dg)*D;
  for(int k=threadIdx.x;k<D;k+=256){
    WihP[(size_t)np*D+k] = f2u(Wih[src+k]);
    WhhP[(size_t)np*D+k] = f2u(Whh[src+k]);
  }
  if(threadIdx.x==0) bsum[np] = bih[g*D+dg] + bhh[g*D+dg];
}

// ---------------- zero init c (fp32) and h0 (bf16) ----------------------------------
__global__ __launch_bounds__(256) void zero_init(float* __restrict__ cbuf, unsigned short* __restrict__ h0){
  size_t i=(size_t)blockIdx.x*256+threadIdx.x;
  if(i<(size_t)B*D){ cbuf[i]=0.f; h0[i]=0; }
}

// ---- xg chunk GEMM (MFMA): xg[R][n'] = shift_row(R) @ WihP[n']^T + bsum[n'] --------
// R = b*TCH + tin, token = b*N + c0 + tin.  M=B*TCH=5120, N=3072, K=768.
__global__ __launch_bounds__(256) void xg_gemm_mfma(
    const unsigned short* __restrict__ shift, const unsigned short* __restrict__ WihP,
    const float* __restrict__ bsum, unsigned short* __restrict__ xgc, int c0){
  __shared__ unsigned short Ash[64*40];
  __shared__ unsigned short Bsh[64*40];
  int tid=threadIdx.x;
  int bx=blockIdx.x, by=blockIdx.y;
  int lane=tid&63, w=tid>>6;
  int wm=w&1, wn=w>>1;
  int srow=tid>>2, skg=(tid&3)*8;
  int l15=lane&15, lq=lane>>4;
  floatx4 acc[2][2]={};
  int R = by*64 + srow;
  int b = R/TCH; int tin = R - b*TCH;
  const unsigned short* aG = shift + ((size_t)b*N + c0 + tin)*D + skg;
  const unsigned short* bG = WihP + (size_t)(bx*64 + srow)*D + skg;
  for(int k0=0;k0<D;k0+=32){
    *(uint4*)&Ash[srow*40 + skg] = *(const uint4*)(aG + k0);
    *(uint4*)&Bsh[srow*40 + skg] = *(const uint4*)(bG + k0);
    __syncthreads();
    short8 a0=*(const short8*)&Ash[(wm*32 + l15)*40 + lq*8];
    short8 a1=*(const short8*)&Ash[(wm*32 + 16 + l15)*40 + lq*8];
    short8 b0=*(const short8*)&Bsh[(wn*32 + l15)*40 + lq*8];
    short8 b1=*(const short8*)&Bsh[(wn*32 + 16 + l15)*40 + lq*8];
    acc[0][0]=__builtin_amdgcn_mfma_f32_16x16x32_bf16(a0,b0,acc[0][0],0,0,0);
    acc[0][1]=__builtin_amdgcn_mfma_f32_16x16x32_bf16(a0,b1,acc[0][1],0,0,0);
    acc[1][0]=__builtin_amdgcn_mfma_f32_16x16x32_bf16(a1,b0,acc[1][0],0,0,0);
    acc[1][1]=__builtin_amdgcn_mfma_f32_16x16x32_bf16(a1,b1,acc[1][1],0,0,0);
    __syncthreads();
  }
  #pragma unroll
  for(int tm=0;tm<2;tm++){
    #pragma unroll
    for(int tn=0;tn<2;tn++){
      int n = bx*64 + wn*32 + tn*16 + l15;
      float bs = bsum[n];
      #pragma unroll
      for(int r=0;r<4;r++){
        int m = wm*32 + tm*16 + lq*4 + r;
        size_t Rg = (size_t)by*64 + m;
        xgc[Rg*G4 + n] = f2u(acc[tm][tn][r] + bs);
      }
    }
  }
}

// ---- LSTM step (MFMA): gates = h@WhhP^T + xg; fused pointwise epilogue -------------
__global__ __launch_bounds__(256) void lstm_step_mfma(
    const unsigned short* __restrict__ hprev, unsigned short* __restrict__ hnext,
    float* __restrict__ cbuf, const unsigned short* __restrict__ xgc,
    const unsigned short* __restrict__ WhhP,
    const float* __restrict__ text, const float* __restrict__ att_t,
    float* __restrict__ out, int t, int tin){
  __shared__ unsigned short Ash[64*40];
  __shared__ unsigned short Bsh[64*40];
  __shared__ float gbuf[64][65];
  int tid=threadIdx.x;
  int bx=blockIdx.x, by=blockIdx.y;   // bx: 48 n'-tiles (16 dg x 4 gates), by: 8 batch tiles
  int lane=tid&63, w=tid>>6;
  int wm=w&1, wn=w>>1;
  int srow=tid>>2, skg=(tid&3)*8;
  int l15=lane&15, lq=lane>>4;
  floatx4 acc[2][2]={};
  const unsigned short* aG = hprev + (size_t)(by*64 + srow)*D + skg;
  const unsigned short* bG = WhhP + (size_t)(bx*64 + srow)*D + skg;
  for(int k0=0;k0<D;k0+=32){
    *(uint4*)&Ash[srow*40 + skg] = *(const uint4*)(aG + k0);
    *(uint4*)&Bsh[srow*40 + skg] = *(const uint4*)(bG + k0);
    __syncthreads();
    short8 a0=*(const short8*)&Ash[(wm*32 + l15)*40 + lq*8];
    short8 a1=*(const short8*)&Ash[(wm*32 + 16 + l15)*40 + lq*8];
    short8 b0=*(const short8*)&Bsh[(wn*32 + l15)*40 + lq*8];
    short8 b1=*(const short8*)&Bsh[(wn*32 + 16 + l15)*40 + lq*8];
    acc[0][0]=__builtin_amdgcn_mfma_f32_16x16x32_bf16(a0,b0,acc[0][0],0,0,0);
    acc[0][1]=__builtin_amdgcn_mfma_f32_16x16x32_bf16(a0,b1,acc[0][1],0,0,0);
    acc[1][0]=__builtin_amdgcn_mfma_f32_16x16x32_bf16(a1,b0,acc[1][0],0,0,0);
    acc[1][1]=__builtin_amdgcn_mfma_f32_16x16x32_bf16(a1,b1,acc[1][1],0,0,0);
    __syncthreads();
  }
  #pragma unroll
  for(int tm=0;tm<2;tm++){
    #pragma unroll
    for(int tn=0;tn<2;tn++){
      int m = wm*32 + tm*16 + lq*4;
      int n = wn*32 + tn*16 + l15;
      #pragma unroll
      for(int r=0;r<4;r++) gbuf[m+r][n]=acc[tm][tn][r];
    }
  }
  __syncthreads();
  for(int p=tid;p<1024;p+=256){
    int bl=p>>4, dgl=p&15;
    int b=by*64+bl, dg=bx*16+dgl;
    size_t xr=((size_t)b*TCH + tin)*G4 + bx*64 + dgl*4;
    float gi=gbuf[bl][dgl*4+0] + u2f(xgc[xr+0]);
    float gf=gbuf[bl][dgl*4+1] + u2f(xgc[xr+1]);
    float gg=gbuf[bl][dgl*4+2] + u2f(xgc[xr+2]);
    float go=gbuf[bl][dgl*4+3] + u2f(xgc[xr+3]);
    float c_old=cbuf[(size_t)b*D+dg];
    float cn=sigf(gf)*c_old + sigf(gi)*tanhf(gg);
    float hn=sigf(go)*tanhf(cn);
    cbuf[(size_t)b*D+dg]=cn;
    hnext[(size_t)b*D+dg]=f2u(hn);
    size_t oidx=((size_t)b*N+t)*D+dg;
    int ch=(t*D+dg)/50;
    out[oidx]=hn + text[oidx]*att_t[(size_t)b*D+ch];
  }
}

extern "C" void kernel_launch(void* const* d_in, const int* in_sizes, int n_in,
                              void* d_out, int out_size, void* d_ws, size_t ws_size,
                              hipStream_t stream){
  const float* text=(const float*)d_in[0];
  const int*  vid =(const int*) d_in[1];
  const int*  aid =(const int*) d_in[2];
  const float* vemb=(const float*)d_in[3];
  const float* aemb=(const float*)d_in[4];
  const float* egw =(const float*)d_in[5];
  const float* Wih =(const float*)d_in[6];
  const float* Whh =(const float*)d_in[7];
  const float* bih =(const float*)d_in[8];
  const float* bhh =(const float*)d_in[9];
  const float* lng =(const float*)d_in[10];
  const float* lnb =(const float*)d_in[11];
  const float* cW  =(const float*)d_in[12];
  const float* cb  =(const float*)d_in[13];
  const float* hW  =(const float*)d_in[14];
  const float* hb  =(const float*)d_in[15];
  const float* vW  =(const float*)d_in[20];
  const float* vb  =(const float*)d_in[21];
  float* out = (float*)d_out;

  // ---- workspace layout (~95 MB) ----
  float* W = (float*)d_ws;
  const size_t S = (size_t)B*D;          // 393216
  float* att_t = W;
  float* att_v = att_t + S;
  float* att_a = att_v + S;
  float* tsum  = att_a + S;
  float* vsum  = tsum + S;
  float* asum  = vsum + S;
  float* fcross= asum + S;
  float* cbuf  = fcross + S;             // 8*S fp32 = 12.6 MB
  int*   m1    = (int*)(cbuf + S);
  int*   m2    = m1 + B;
  float* bsum  = (float*)(m2 + B);       // G4 fp32
  unsigned short* WihP = (unsigned short*)(bsum + G4);   // G4*D
  unsigned short* WhhP = WihP + (size_t)G4*D;            // G4*D
  unsigned short* hA0  = WhhP + (size_t)G4*D;            // S
  unsigned short* hA1  = hA0 + S;                        // S
  bf16*  shift = (bf16*)(hA1 + S);                       // BN*D bf16 = 39.3 MB
  unsigned short* xgc  = (unsigned short*)(shift + (size_t)BN*D); // B*TCH*G4 = 31.5 MB

  prep_weights<<<G4,256,0,stream>>>(Wih,Whh,bih,bhh,WihP,WhhP,bsum);
  egce_att<<<B,256,0,stream>>>(text,vid,aid,vemb,aemb,egw,att_t,att_v,att_a);
  gate_sums<<<B,256,0,stream>>>(text,vid,aid,vemb,aemb,att_t,att_v,att_a,
                                tsum,vsum,asum);
  cos_masks<<<B,256,0,stream>>>(tsum,vsum,asum,m1,m2);
  fcross_gemm<<<dim3(12,8),256,0,stream>>>(vsum,asum,vW,vb,fcross);
  fuse_pre<<<(unsigned)(((size_t)BN*D)/256),256,0,stream>>>(text,att_t,fcross,shift);
  cond_fusion<<<B,256,0,stream>>>(m1,m2,0,vid,aid,vemb,aemb,att_t,att_v,att_a,cW,cb,text,shift);
  cond_fusion<<<B,256,0,stream>>>(m1,m2,1,vid,aid,vemb,aemb,att_t,att_v,att_a,hW,hb,text,shift);
  ln_rows<<<BN,256,0,stream>>>(shift,lng,lnb);
  zero_init<<<(unsigned)((S+255)/256),256,0,stream>>>(cbuf,hA0);

  int t=0;
  for(int c=0;c<NCHUNK;c++){
    xg_gemm_mfma<<<dim3(48, (B*TCH)/64),256,0,stream>>>((const unsigned short*)shift,WihP,bsum,xgc,c*TCH);
    for(int ti=0;ti<TCH;ti++,t++){
      unsigned short* hp = (t&1)? hA1 : hA0;
      unsigned short* hn = (t&1)? hA0 : hA1;
      lstm_step_mfma<<<dim3(48,8),256,0,stream>>>(hp,hn,cbuf,xgc,WhhP,text,att_t,out,t,ti);
    }
  }
}

// Round 5
// 1463.578 us; speedup vs baseline: 6.6745x; 1.2154x over previous
//
#include <hip/hip_runtime.h>
#include <hip/hip_bf16.h>
#include <math.h>

#define B 512
#define N 50
#define D 768
#define G4 3072
#define BN (B*N)        // 25600
#define FLAT (N*D)      // 38400
#define TCH 10          // timesteps per xg chunk
#define NCHUNK (N/TCH)  // 5
#define KC 1536         // fcross K (vsum|asum concat)

typedef __hip_bfloat16 bf16;
typedef short short8 __attribute__((ext_vector_type(8)));
typedef float floatx4 __attribute__((ext_vector_type(4)));

__device__ __forceinline__ float sigf(float x){ return 1.0f/(1.0f+expf(-x)); }
__device__ __forceinline__ float u2f(unsigned short u){ return __uint_as_float(((unsigned int)u)<<16); }
__device__ __forceinline__ unsigned short f2u(float f){ bf16 h=__float2bfloat16(f); return *(unsigned short*)&h; }

// ---------------- Kernel A: EGCE channel means + attention gates --------------------
__global__ __launch_bounds__(256) void egce_att(
    const float* __restrict__ text, const int* __restrict__ vid, const int* __restrict__ aid,
    const float* __restrict__ vemb, const float* __restrict__ aemb, const float* __restrict__ egw,
    float* __restrict__ att_t, float* __restrict__ att_v, float* __restrict__ att_a){
  int b = blockIdx.x; int tid = threadIdx.x;
  __shared__ float gt[D+2], gv[D+2], ga[D+2];
  float w0 = egw[0], w1 = egw[1], w2 = egw[2];
  if(tid==0){ gt[0]=gv[0]=ga[0]=0.f; gt[D+1]=gv[D+1]=ga[D+1]=0.f; }
  const float* tb = text + (size_t)b*FLAT;
  const int* vb_ = vid + b*N; const int* ab_ = aid + b*N;
  for(int ch = tid; ch < D; ch += 256){
    float st=0.f, sv=0.f, sa=0.f;
    int j0 = ch*50;
    for(int p=0;p<50;p++){
      int j = j0+p; int n = j/D; int d = j - n*D;
      st += tb[j];
      float vv = vemb[vb_[n]*D + d]; sv += vv>0.f?vv:0.f;
      sa += aemb[ab_[n]*D + d];
    }
    gt[ch+1]=st*(1.f/50.f); gv[ch+1]=sv*(1.f/50.f); ga[ch+1]=sa*(1.f/50.f);
  }
  __syncthreads();
  for(int ch = tid; ch < D; ch += 256){
    att_t[b*D+ch] = sigf(w0*gt[ch]+w1*gt[ch+1]+w2*gt[ch+2]);
    att_v[b*D+ch] = sigf(w0*gv[ch]+w1*gv[ch+1]+w2*gv[ch+2]);
    att_a[b*D+ch] = sigf(w0*ga[ch]+w1*ga[ch+1]+w2*ga[ch+2]);
  }
}

// ---- Kernel B: per-batch gated sums of v/a embeddings -> catAB bf16 [B][1536] ------
// (text-gated sums fed only the provably-dead cosine masks; dropped.)
__global__ __launch_bounds__(256) void gate_sums2(
    const int* __restrict__ vid, const int* __restrict__ aid,
    const float* __restrict__ vemb, const float* __restrict__ aemb,
    const float* __restrict__ att_v, const float* __restrict__ att_a,
    unsigned short* __restrict__ catAB){
  int b = blockIdx.x; int tid = threadIdx.x;
  float va[3]={0,0,0}, aa[3]={0,0,0};
  const float* Av = att_v + b*D; const float* Aa = att_a + b*D;
  for(int n=0;n<N;n++){
    int id_v = vid[b*N+n]; int id_a = aid[b*N+n];
    for(int q=0;q<3;q++){
      int d = q*256 + tid;
      int ch = (n*D + d)/50;
      float vv = vemb[id_v*D+d]; vv = vv>0.f?vv:0.f;
      va[q] += vv * Av[ch];
      aa[q] += aemb[id_a*D+d] * Aa[ch];
    }
  }
  for(int q=0;q<3;q++){
    int d=q*256+tid;
    catAB[(size_t)b*KC + d]     = f2u(va[q]);
    catAB[(size_t)b*KC + D + d] = f2u(aa[q]);
  }
}

// ---- weight prep: LSTM gate-interleave n'=dg*4+g (bf16) + bias sums ----------------
__global__ __launch_bounds__(256) void prep_weights(
    const float* __restrict__ Wih, const float* __restrict__ Whh,
    const float* __restrict__ bih, const float* __restrict__ bhh,
    unsigned short* __restrict__ WihP, unsigned short* __restrict__ WhhP,
    float* __restrict__ bsum){
  int np = blockIdx.x;            // 0..3071
  int dg = np>>2, g = np&3;       // hidden unit, gate (i,f,g,o)
  size_t src = (size_t)(g*D+dg)*D;
  for(int k=threadIdx.x;k<D;k+=256){
    WihP[(size_t)np*D+k] = f2u(Wih[src+k]);
    WhhP[(size_t)np*D+k] = f2u(Whh[src+k]);
  }
  if(threadIdx.x==0) bsum[np] = bih[g*D+dg] + bhh[g*D+dg];
}

// ---- fcross weight prep: WcB[n][0:768]=W0, [768:1536]=W1+W2 (bf16); fb=50*(b0+b1+b2)
__global__ __launch_bounds__(256) void prep_fcross(
    const float* __restrict__ vW, const float* __restrict__ vb,
    unsigned short* __restrict__ WcB, float* __restrict__ fb){
  int n = blockIdx.x;             // 0..767
  const float* W0 = vW; const float* W1 = vW + D*D; const float* W2 = vW + 2*D*D;
  for(int k=threadIdx.x;k<D;k+=256){
    WcB[(size_t)n*KC + k]     = f2u(W0[(size_t)n*D+k]);
    WcB[(size_t)n*KC + D + k] = f2u(W1[(size_t)n*D+k] + W2[(size_t)n*D+k]);
  }
  if(threadIdx.x==0) fb[n] = 50.f*(vb[n]+vb[D+n]+vb[2*D+n]);
}

// ---- fcross MFMA: fcross[b][n] = (catAB[b] . WcB[n] + fb[n]) / 3 -------------------
// M=512 (32-tiles, by 0..15), N=768 (64-tiles, bx 0..11), K=1536.
__global__ __launch_bounds__(256) void fcross_mfma(
    const unsigned short* __restrict__ catAB, const unsigned short* __restrict__ WcB,
    const float* __restrict__ fb, float* __restrict__ fcross){
  __shared__ unsigned short Ash[32*40];
  __shared__ unsigned short Bsh[64*40];
  int tid=threadIdx.x;
  int bx=blockIdx.x, by=blockIdx.y;
  int lane=tid&63, w=tid>>6;
  int l15=lane&15, lq=lane>>4;
  int arow=tid>>3, aseg=(tid&7)*4;      // A: 32 rows x 32 cols, 8B each
  int brow=tid>>2, bseg=(tid&3)*8;      // B: 64 rows x 32 cols, 16B each
  floatx4 acc0={},acc1={};
  const unsigned short* aG = catAB + (size_t)(by*32 + arow)*KC + aseg;
  const unsigned short* bG = WcB   + (size_t)(bx*64 + brow)*KC + bseg;
  for(int k0=0;k0<KC;k0+=32){
    *(uint2*)&Ash[arow*40 + aseg] = *(const uint2*)(aG + k0);
    *(uint4*)&Bsh[brow*40 + bseg] = *(const uint4*)(bG + k0);
    __syncthreads();
    short8 a0=*(const short8*)&Ash[l15*40 + lq*8];
    short8 a1=*(const short8*)&Ash[(16+l15)*40 + lq*8];
    short8 bb=*(const short8*)&Bsh[(w*16 + l15)*40 + lq*8];
    acc0=__builtin_amdgcn_mfma_f32_16x16x32_bf16(a0,bb,acc0,0,0,0);
    acc1=__builtin_amdgcn_mfma_f32_16x16x32_bf16(a1,bb,acc1,0,0,0);
    __syncthreads();
  }
  int n = bx*64 + w*16 + l15;
  float bias = fb[n];
  #pragma unroll
  for(int r=0;r<4;r++){
    int m0 = by*32 + lq*4 + r;
    fcross[(size_t)m0*D + n]      = (acc0[r] + bias)*(1.f/3.f);
    fcross[(size_t)(m0+16)*D + n] = (acc1[r] + bias)*(1.f/3.f);
  }
}

// ---- fused pre-LN + LayerNorm: shift = LN(fcross[b] + text*att_t) ------------------
__global__ __launch_bounds__(256) void fuse_ln(
    const float* __restrict__ text, const float* __restrict__ att_t,
    const float* __restrict__ fcross, const float* __restrict__ lng,
    const float* __restrict__ lnb, bf16* __restrict__ shift){
  int row = blockIdx.x;           // 0..BN-1
  int b = row/N, n = row - b*N;
  int tid=threadIdx.x;
  float v[3];
  for(int q=0;q<3;q++){
    int d=q*256+tid;
    int ch=(n*D+d)/50;
    v[q] = text[(size_t)row*D+d]*att_t[(size_t)b*D+ch] + fcross[(size_t)b*D+d];
  }
  __shared__ float red[256];
  red[tid]=v[0]+v[1]+v[2]; __syncthreads();
  for(int st=128;st>0;st>>=1){ if(tid<st) red[tid]+=red[tid+st]; __syncthreads(); }
  float m = red[0]*(1.f/768.f);
  __syncthreads();
  float s2=0.f;
  for(int q=0;q<3;q++){ float dl=v[q]-m; s2+=dl*dl; }
  red[tid]=s2; __syncthreads();
  for(int st=128;st>0;st>>=1){ if(tid<st) red[tid]+=red[tid+st]; __syncthreads(); }
  float var = red[0]*(1.f/768.f);
  float rs = 1.f/sqrtf(var+1e-5f);
  for(int q=0;q<3;q++){
    int d=q*256+tid;
    shift[(size_t)row*D+d]=__float2bfloat16((v[q]-m)*rs*lng[d]+lnb[d]);
  }
}

// ---------------- zero init c (fp32) and h0 (bf16) ----------------------------------
__global__ __launch_bounds__(256) void zero_init(float* __restrict__ cbuf, unsigned short* __restrict__ h0){
  size_t i=(size_t)blockIdx.x*256+threadIdx.x;
  if(i<(size_t)B*D){ cbuf[i]=0.f; h0[i]=0; }
}

// ---- xg chunk GEMM (MFMA): xg[R][n'] = shift_row(R) @ WihP[n']^T + bsum[n'] --------
__global__ __launch_bounds__(256) void xg_gemm_mfma(
    const unsigned short* __restrict__ shift, const unsigned short* __restrict__ WihP,
    const float* __restrict__ bsum, unsigned short* __restrict__ xgc, int c0){
  __shared__ unsigned short Ash[64*40];
  __shared__ unsigned short Bsh[64*40];
  int tid=threadIdx.x;
  int bx=blockIdx.x, by=blockIdx.y;
  int lane=tid&63, w=tid>>6;
  int wm=w&1, wn=w>>1;
  int srow=tid>>2, skg=(tid&3)*8;
  int l15=lane&15, lq=lane>>4;
  floatx4 acc[2][2]={};
  int R = by*64 + srow;
  int b = R/TCH; int tin = R - b*TCH;
  const unsigned short* aG = shift + ((size_t)b*N + c0 + tin)*D + skg;
  const unsigned short* bG = WihP + (size_t)(bx*64 + srow)*D + skg;
  for(int k0=0;k0<D;k0+=32){
    *(uint4*)&Ash[srow*40 + skg] = *(const uint4*)(aG + k0);
    *(uint4*)&Bsh[srow*40 + skg] = *(const uint4*)(bG + k0);
    __syncthreads();
    short8 a0=*(const short8*)&Ash[(wm*32 + l15)*40 + lq*8];
    short8 a1=*(const short8*)&Ash[(wm*32 + 16 + l15)*40 + lq*8];
    short8 b0=*(const short8*)&Bsh[(wn*32 + l15)*40 + lq*8];
    short8 b1=*(const short8*)&Bsh[(wn*32 + 16 + l15)*40 + lq*8];
    acc[0][0]=__builtin_amdgcn_mfma_f32_16x16x32_bf16(a0,b0,acc[0][0],0,0,0);
    acc[0][1]=__builtin_amdgcn_mfma_f32_16x16x32_bf16(a0,b1,acc[0][1],0,0,0);
    acc[1][0]=__builtin_amdgcn_mfma_f32_16x16x32_bf16(a1,b0,acc[1][0],0,0,0);
    acc[1][1]=__builtin_amdgcn_mfma_f32_16x16x32_bf16(a1,b1,acc[1][1],0,0,0);
    __syncthreads();
  }
  #pragma unroll
  for(int tm=0;tm<2;tm++){
    #pragma unroll
    for(int tn=0;tn<2;tn++){
      int n = bx*64 + wn*32 + tn*16 + l15;
      float bs = bsum[n];
      #pragma unroll
      for(int r=0;r<4;r++){
        int m = wm*32 + tm*16 + lq*4 + r;
        size_t Rg = (size_t)by*64 + m;
        xgc[Rg*G4 + n] = f2u(acc[tm][tn][r] + bs);
      }
    }
  }
}

// ---- LSTM step (MFMA, 32x64 tiles, 768 blocks = 3/CU) ------------------------------
__global__ __launch_bounds__(256) void lstm_step_mfma(
    const unsigned short* __restrict__ hprev, unsigned short* __restrict__ hnext,
    float* __restrict__ cbuf, const unsigned short* __restrict__ xgc,
    const unsigned short* __restrict__ WhhP,
    const float* __restrict__ text, const float* __restrict__ att_t,
    float* __restrict__ out, int t, int tin){
  __shared__ unsigned short Ash[32*40];
  __shared__ unsigned short Bsh[64*40];
  __shared__ float gbuf[32][65];
  int tid=threadIdx.x;
  int bx=blockIdx.x, by=blockIdx.y;   // bx: 48 n'-tiles of 64; by: 16 batch tiles of 32
  int lane=tid&63, w=tid>>6;
  int l15=lane&15, lq=lane>>4;
  int arow=tid>>3, aseg=(tid&7)*4;
  int brow=tid>>2, bseg=(tid&3)*8;
  floatx4 acc0={},acc1={};
  const unsigned short* aG = hprev + (size_t)(by*32 + arow)*D + aseg;
  const unsigned short* bG = WhhP + (size_t)(bx*64 + brow)*D + bseg;
  for(int k0=0;k0<D;k0+=32){
    *(uint2*)&Ash[arow*40 + aseg] = *(const uint2*)(aG + k0);
    *(uint4*)&Bsh[brow*40 + bseg] = *(const uint4*)(bG + k0);
    __syncthreads();
    short8 a0=*(const short8*)&Ash[l15*40 + lq*8];
    short8 a1=*(const short8*)&Ash[(16+l15)*40 + lq*8];
    short8 bb=*(const short8*)&Bsh[(w*16 + l15)*40 + lq*8];
    acc0=__builtin_amdgcn_mfma_f32_16x16x32_bf16(a0,bb,acc0,0,0,0);
    acc1=__builtin_amdgcn_mfma_f32_16x16x32_bf16(a1,bb,acc1,0,0,0);
    __syncthreads();
  }
  {
    int n = w*16 + l15;
    #pragma unroll
    for(int r=0;r<4;r++){
      gbuf[lq*4+r][n]      = acc0[r];
      gbuf[16+lq*4+r][n]   = acc1[r];
    }
  }
  __syncthreads();
  for(int p=tid;p<512;p+=256){
    int bl=p>>4, dgl=p&15;
    int b=by*32+bl, dg=bx*16+dgl;
    size_t xr=((size_t)b*TCH + tin)*G4 + bx*64 + dgl*4;
    float gi=gbuf[bl][dgl*4+0] + u2f(xgc[xr+0]);
    float gf=gbuf[bl][dgl*4+1] + u2f(xgc[xr+1]);
    float gg=gbuf[bl][dgl*4+2] + u2f(xgc[xr+2]);
    float go=gbuf[bl][dgl*4+3] + u2f(xgc[xr+3]);
    float c_old=cbuf[(size_t)b*D+dg];
    float cn=sigf(gf)*c_old + sigf(gi)*tanhf(gg);
    float hn=sigf(go)*tanhf(cn);
    cbuf[(size_t)b*D+dg]=cn;
    hnext[(size_t)b*D+dg]=f2u(hn);
    size_t oidx=((size_t)b*N+t)*D+dg;
    int ch=(t*D+dg)/50;
    out[oidx]=hn + text[oidx]*att_t[(size_t)b*D+ch];
  }
}

extern "C" void kernel_launch(void* const* d_in, const int* in_sizes, int n_in,
                              void* d_out, int out_size, void* d_ws, size_t ws_size,
                              hipStream_t stream){
  const float* text=(const float*)d_in[0];
  const int*  vid =(const int*) d_in[1];
  const int*  aid =(const int*) d_in[2];
  const float* vemb=(const float*)d_in[3];
  const float* aemb=(const float*)d_in[4];
  const float* egw =(const float*)d_in[5];
  const float* Wih =(const float*)d_in[6];
  const float* Whh =(const float*)d_in[7];
  const float* bih =(const float*)d_in[8];
  const float* bhh =(const float*)d_in[9];
  const float* lng =(const float*)d_in[10];
  const float* lnb =(const float*)d_in[11];
  const float* vW  =(const float*)d_in[20];
  const float* vb  =(const float*)d_in[21];
  float* out = (float*)d_out;

  // ---- workspace layout (~93 MB, inside proven-safe region) ----
  float* W = (float*)d_ws;
  const size_t S = (size_t)B*D;          // 393216
  float* att_t = W;
  float* att_v = att_t + S;
  float* att_a = att_v + S;
  float* fcross= att_a + S;
  float* cbuf  = fcross + S;             // 5*S fp32
  float* bsum  = cbuf + S;               // G4
  float* fb    = bsum + G4;              // D
  unsigned short* WihP = (unsigned short*)(fb + D);      // G4*D
  unsigned short* WhhP = WihP + (size_t)G4*D;            // G4*D
  unsigned short* WcB  = WhhP + (size_t)G4*D;            // D*KC
  unsigned short* catAB= WcB + (size_t)D*KC;             // B*KC
  unsigned short* hA0  = catAB + (size_t)B*KC;           // S
  unsigned short* hA1  = hA0 + S;                        // S
  bf16*  shift = (bf16*)(hA1 + S);                       // BN*D bf16
  unsigned short* xgc  = (unsigned short*)(shift + (size_t)BN*D); // B*TCH*G4

  prep_weights<<<G4,256,0,stream>>>(Wih,Whh,bih,bhh,WihP,WhhP,bsum);
  prep_fcross<<<D,256,0,stream>>>(vW,vb,WcB,fb);
  egce_att<<<B,256,0,stream>>>(text,vid,aid,vemb,aemb,egw,att_t,att_v,att_a);
  gate_sums2<<<B,256,0,stream>>>(vid,aid,vemb,aemb,att_v,att_a,catAB);
  fcross_mfma<<<dim3(12,16),256,0,stream>>>(catAB,WcB,fb,fcross);
  fuse_ln<<<BN,256,0,stream>>>(text,att_t,fcross,lng,lnb,shift);
  zero_init<<<(unsigned)((S+255)/256),256,0,stream>>>(cbuf,hA0);

  int t=0;
  for(int c=0;c<NCHUNK;c++){
    xg_gemm_mfma<<<dim3(48, (B*TCH)/64),256,0,stream>>>((const unsigned short*)shift,WihP,bsum,xgc,c*TCH);
    for(int ti=0;ti<TCH;ti++,t++){
      unsigned short* hp = (t&1)? hA1 : hA0;
      unsigned short* hn = (t&1)? hA0 : hA1;
      lstm_step_mfma<<<dim3(48,16),256,0,stream>>>(hp,hn,cbuf,xgc,WhhP,text,att_t,out,t,ti);
    }
  }
}